// Round 1
// baseline (204.697 us; speedup 1.0000x reference)
//
#include <hip/hip_runtime.h>

// ---------- types / helpers ----------
typedef _Float16 f16x8 __attribute__((ext_vector_type(8)));
typedef float f32x4 __attribute__((ext_vector_type(4)));

__device__ __forceinline__ float tanh_fast(float x){
  // tanh(x) = 1 - 2/(1+exp2(2*log2e*x)); exact at saturation (inf -> 1, 0 -> -1)
  float e = __builtin_amdgcn_exp2f(x * 2.88539008177793f);
  return 1.f - 2.f * __builtin_amdgcn_rcpf(1.f + e);
}
__device__ __forceinline__ unsigned short f2h(float f){
  return __builtin_bit_cast(unsigned short, (_Float16)f);
}
__device__ __forceinline__ float h2f(unsigned short u){
  return (float)__builtin_bit_cast(_Float16, u);
}
__device__ __forceinline__ f32x4 mfma16(f16x8 a, f16x8 b, f32x4 c){
  return __builtin_amdgcn_mfma_f32_16x16x32_f16(a, b, c, 0, 0, 0);
}

// A-fragment from an LDS [32][128] f16 tile.
// MFMA 16x16x32: lane holds A[row=lane&15][k0=8*(lane>>4) + j], j=0..7 (per 32-K step s)
__device__ __forceinline__ f16x8 ldsA(const unsigned short* buf, int rb, int s, int lane){
  return *(const f16x8*)(buf + (rb*16 + (lane&15))*128 + s*32 + ((lane>>4)<<3));
}

// ---------- weight transpose+convert: in f32 [R][C] -> out f16 [C][R] ----------
__global__ void tconv_kernel(const float* __restrict__ in, unsigned short* __restrict__ out,
                             int R, int C){
  __shared__ float t[32][33];
  int c0 = blockIdx.x*32, r0 = blockIdx.y*32;
  int tx = threadIdx.x, ty = threadIdx.y;
  #pragma unroll
  for (int j=ty; j<32; j+=8) t[j][tx] = in[(size_t)(r0+j)*C + c0 + tx];
  __syncthreads();
  #pragma unroll
  for (int j=ty; j<32; j+=8) out[(size_t)(c0+j)*R + r0 + tx] = f2h(t[tx][j]);
}

// ---------- K1: h = tanh(x @ hw1 + hb1), x built from obs; h stored f16 ----------
__global__ __launch_bounds__(256) void k1_hidden(const float* __restrict__ obs,
    const float* __restrict__ hw1, const float* __restrict__ hb1,
    unsigned short* __restrict__ h16){
  __shared__ float w_s[96*128];
  __shared__ float x_s[16*96];
  __shared__ float b_s[128];
  int t = threadIdx.x;
  for (int idx=t; idx<96*128; idx+=256) w_s[idx] = hw1[idx];
  if (t < 128) b_s[t] = hb1[t];
  int n0 = blockIdx.x * 16;
  for (int idx=t; idx<16*96; idx+=256){
    int r = idx/96, i = idx - r*96;
    int n = n0 + r; int b = n>>3, l = n&7;
    x_s[idx] = (i<64) ? obs[b*360 + i] : obs[b*360 + 104 + (l<<5) + (i-64)];
  }
  __syncthreads();
  for (int e=t; e<16*128; e+=256){
    int r = e>>7, o = e&127;
    float acc = b_s[o];
    const float* xr = &x_s[r*96];
    #pragma unroll 4
    for (int i=0;i<96;++i) acc = fmaf(xr[i], w_s[i*128+o], acc);
    h16[(size_t)(n0+r)*128 + o] = f2h(tanh_fast(acc));
  }
}

// ---------- K2: fused hypernet GEMM + tanh + x-contraction + emb/mean ----------
// grid 256 (32 rows each), block 512 (8 waves); wave w handles i in [w*12, w*12+12)
__global__ __launch_bounds__(512) void k2_hyper(const float* __restrict__ obs,
    const unsigned short* __restrict__ h16, const unsigned short* __restrict__ wt2,
    const float* __restrict__ hb2,
    unsigned short* __restrict__ emb16, unsigned short* __restrict__ mean16){
  __shared__ float x_s[32*96];
  __shared__ float acc_s[32*128];
  int t = threadIdx.x;
  int lane = t & 63, w = t >> 6;
  int R0 = blockIdx.x * 32;

  for (int idx=t; idx<32*96; idx+=512){
    int r = idx/96, i = idx - r*96;
    int n = R0 + r; int b = n>>3, l = n&7;
    x_s[idx] = (i<64) ? obs[b*360 + i] : obs[b*360 + 104 + (l<<5) + (i-64)];
  }
  for (int idx=t; idx<32*128; idx+=512) acc_s[idx] = 0.f;

  // A fragments: rows R0 + rb*16 + (lane&15), all 4 K-steps, from global h16 (f16)
  int kof = (lane>>4) << 3;
  f16x8 afrag[2][4];
  #pragma unroll
  for (int rb=0; rb<2; ++rb)
    #pragma unroll
    for (int s=0; s<4; ++s)
      afrag[rb][s] = *(const f16x8*)(h16 + (size_t)(R0 + rb*16 + (lane&15))*128 + s*32 + kof);

  __syncthreads();

  float facc[2][8][4];
  #pragma unroll
  for (int rb=0;rb<2;++rb)
    #pragma unroll
    for (int ob=0;ob<8;++ob)
      #pragma unroll
      for (int reg=0;reg<4;++reg) facc[rb][ob][reg] = 0.f;

  int rloc = (lane>>4) << 2;  // C-layout row base: row = 4*(lane>>4)+reg
  for (int il=0; il<12; ++il){
    int ii = w*12 + il;
    float xw[2][4];
    #pragma unroll
    for (int rb=0;rb<2;++rb)
      #pragma unroll
      for (int reg=0;reg<4;++reg)
        xw[rb][reg] = x_s[(rb*16 + rloc + reg)*96 + ii];
    #pragma unroll
    for (int ob=0; ob<8; ++ob){
      int c = ii*128 + ob*16 + (lane&15);        // w_flat column (= Wt2 row)
      const unsigned short* wr = wt2 + (size_t)c*128 + kof;
      f32x4 a0 = {0.f,0.f,0.f,0.f}, a1v = {0.f,0.f,0.f,0.f};
      #pragma unroll
      for (int s=0;s<4;++s){
        f16x8 bf = *(const f16x8*)(wr + s*32);
        a0  = mfma16(afrag[0][s], bf, a0);
        a1v = mfma16(afrag[1][s], bf, a1v);
      }
      float bias = hb2[c];
      #pragma unroll
      for (int reg=0;reg<4;++reg){
        facc[0][ob][reg] = fmaf(xw[0][reg], tanh_fast(a0[reg]+bias),  facc[0][ob][reg]);
        facc[1][ob][reg] = fmaf(xw[1][reg], tanh_fast(a1v[reg]+bias), facc[1][ob][reg]);
      }
    }
  }
  // combine partial sums across waves
  #pragma unroll
  for (int rb=0;rb<2;++rb)
    #pragma unroll
    for (int ob=0;ob<8;++ob)
      #pragma unroll
      for (int reg=0;reg<4;++reg)
        atomicAdd(&acc_s[(rb*16 + rloc + reg)*128 + ob*16 + (lane&15)], facc[rb][ob][reg]);
  __syncthreads();
  for (int idx=t; idx<32*128; idx+=512){
    float e = tanh_fast(acc_s[idx]);
    acc_s[idx] = e;
    int r = idx>>7, o = idx&127;
    emb16[(size_t)(R0+r)*128 + o] = f2h(e);
  }
  __syncthreads();
  {
    int b_loc = t>>7, o = t&127;   // 4 batches x 128 = 512 = blockDim
    float m = 0.f;
    #pragma unroll
    for (int l=0;l<8;++l) m += acc_s[(b_loc*8+l)*128 + o];
    mean16[(size_t)(R0/8 + b_loc)*128 + o] = f2h(m * 0.125f);
  }
}

// ---------- K4: fused MLP chain + softmax + final ----------
// One GEMM stage: out = tanh(in @ W^T-stored + bias). KS = K/32. Dual A-source for K=256.
template<int KS>
__device__ __forceinline__ void stage(const unsigned short* inA, const unsigned short* inB,
    const unsigned short* wt, const float* bias, unsigned short* outb, int w, int lane){
  #pragma unroll
  for (int obl=0; obl<2; ++obl){
    int col = ((w*2+obl)<<4) + (lane&15);
    f32x4 a0 = {0.f,0.f,0.f,0.f}, a1v = {0.f,0.f,0.f,0.f};
    #pragma unroll
    for (int s=0;s<KS;++s){
      f16x8 bfr = *(const f16x8*)(wt + (size_t)col*(KS*32) + s*32 + ((lane>>4)<<3));
      f16x8 aa0, aa1;
      if (KS==8 && s>=4){ aa0 = ldsA(inB,0,s-4,lane); aa1 = ldsA(inB,1,s-4,lane); }
      else              { aa0 = ldsA(inA,0,s,lane);   aa1 = ldsA(inA,1,s,lane);   }
      a0  = mfma16(aa0, bfr, a0);
      a1v = mfma16(aa1, bfr, a1v);
    }
    float bb = bias[col];
    #pragma unroll
    for (int reg=0;reg<4;++reg){
      int r0 = ((lane>>4)<<2) + reg;
      outb[r0*128 + col]      = f2h(tanh_fast(a0[reg] + bb));
      outb[(16+r0)*128 + col] = f2h(tanh_fast(a1v[reg] + bb));
    }
  }
}

__global__ __launch_bounds__(256) void k4_mlp(
    const unsigned short* __restrict__ emb16, const unsigned short* __restrict__ mean16,
    const unsigned short* __restrict__ vw1t, const unsigned short* __restrict__ vw2t,
    const unsigned short* __restrict__ aw1t, const unsigned short* __restrict__ aw2t,
    const float* __restrict__ vb1, const float* __restrict__ vb2,
    const float* __restrict__ ab1, const float* __restrict__ ab2,
    const float* __restrict__ aw3, const float* __restrict__ ab3,
    float* __restrict__ outp){
  __shared__ unsigned short bufE[32*128];
  __shared__ unsigned short bufM[32*128];
  __shared__ unsigned short bufA[32*128];
  __shared__ float fin[4*128];
  __shared__ float lp[32*8];
  __shared__ float att_s[32];
  int t = threadIdx.x, lane = t&63, w = t>>6;
  int R0 = blockIdx.x*32;

  for (int idx=t; idx<512; idx+=256){
    int r = idx>>4, c8 = (idx&15)<<3;
    int n = R0 + r;
    *(uint4*)(bufE + r*128 + c8) = *(const uint4*)(emb16  + (size_t)n*128 + c8);
    *(uint4*)(bufM + r*128 + c8) = *(const uint4*)(mean16 + (size_t)(n & 1023)*128 + c8); // mean[n % 1024]!
  }
  for (int idx=t; idx<512; idx+=256) fin[idx] = 0.f;
  __syncthreads();

  stage<8>(bufE, bufM, aw1t, ab1, bufA, w, lane);   // a1 = tanh([emb|mean] @ aw1 + ab1)
  __syncthreads();
  stage<4>(bufA, nullptr, aw2t, ab2, bufM, w, lane); // a2
  __syncthreads();
  {
    int r = t>>3, seg = t&7;
    float p = 0.f;
    const unsigned short* row = bufM + r*128 + seg*16;
    const float* w3 = aw3 + seg*16;
    #pragma unroll
    for (int k=0;k<16;++k) p += h2f(row[k]) * w3[k];
    lp[r*8+seg] = p;
  }
  __syncthreads();
  if (t < 4){   // per-batch softmax over 8 landmarks
    float lg[8]; float mx = -1e30f;
    for (int l=0;l<8;++l){
      float s = ab3[0];
      #pragma unroll
      for (int sg=0;sg<8;++sg) s += lp[(t*8+l)*8+sg];
      lg[l] = s; mx = fmaxf(mx, s);
    }
    float sum = 0.f;
    for (int l=0;l<8;++l){ lg[l] = __builtin_amdgcn_exp2f((lg[l]-mx)*1.44269504089f); sum += lg[l]; }
    float inv = __builtin_amdgcn_rcpf(sum);
    for (int l=0;l<8;++l) att_s[t*8+l] = lg[l]*inv;
  }
  __syncthreads();
  stage<4>(bufE, nullptr, vw1t, vb1, bufA, w, lane); // v1
  __syncthreads();
  { // v2 + final weighted accumulation
    #pragma unroll
    for (int obl=0; obl<2; ++obl){
      int col = ((w*2+obl)<<4) + (lane&15);
      f32x4 a0 = {0.f,0.f,0.f,0.f}, a1v = {0.f,0.f,0.f,0.f};
      #pragma unroll
      for (int s=0;s<4;++s){
        f16x8 bfr = *(const f16x8*)(vw2t + (size_t)col*128 + s*32 + ((lane>>4)<<3));
        a0  = mfma16(ldsA(bufA,0,s,lane), bfr, a0);
        a1v = mfma16(ldsA(bufA,1,s,lane), bfr, a1v);
      }
      float bb = vb2[col];
      #pragma unroll
      for (int reg=0;reg<4;++reg){
        int r0 = ((lane>>4)<<2) + reg;
        float v0 = tanh_fast(a0[reg]+bb);
        float v1 = tanh_fast(a1v[reg]+bb);
        atomicAdd(&fin[((r0)>>3)*128 + col],    att_s[r0]    * v0);
        atomicAdd(&fin[((16+r0)>>3)*128 + col], att_s[16+r0] * v1);
      }
    }
  }
  __syncthreads();
  for (int idx=t; idx<512; idx+=256){
    int b_loc = idx>>7, o = idx&127;
    outp[(size_t)(R0/8 + b_loc)*128 + o] = fin[idx];
  }
}

// ---------- launch ----------
extern "C" void kernel_launch(void* const* d_in, const int* in_sizes, int n_in,
                              void* d_out, int out_size, void* d_ws, size_t ws_size,
                              hipStream_t stream){
  const float* obs = (const float*)d_in[0];
  const float* hw1 = (const float*)d_in[3];
  const float* hb1 = (const float*)d_in[4];
  const float* hw2 = (const float*)d_in[5];
  const float* hb2 = (const float*)d_in[6];
  const float* vw1 = (const float*)d_in[7];
  const float* vb1 = (const float*)d_in[8];
  const float* vw2 = (const float*)d_in[9];
  const float* vb2 = (const float*)d_in[10];
  const float* aw1 = (const float*)d_in[11];
  const float* ab1 = (const float*)d_in[12];
  const float* aw2 = (const float*)d_in[13];
  const float* ab2 = (const float*)d_in[14];
  const float* aw3 = (const float*)d_in[15];
  const float* ab3 = (const float*)d_in[16];

  char* ws = (char*)d_ws;
  unsigned short* wt2    = (unsigned short*)(ws);             // 12288*128*2 = 3,145,728
  unsigned short* h16    = (unsigned short*)(ws + 3145728);   // 8192*128*2  = 2,097,152
  unsigned short* emb16  = (unsigned short*)(ws + 5242880);   // 2,097,152
  unsigned short* mean16 = (unsigned short*)(ws + 7340032);   // 1024*128*2  = 262,144
  unsigned short* vw1t   = (unsigned short*)(ws + 7602176);   // 32,768
  unsigned short* vw2t   = (unsigned short*)(ws + 7634944);   // 32,768
  unsigned short* aw1t   = (unsigned short*)(ws + 7667712);   // 65,536
  unsigned short* aw2t   = (unsigned short*)(ws + 7733248);   // 32,768   (end 7,766,016 B)
  float* outp = (float*)d_out;

  tconv_kernel<<<dim3(12288/32, 128/32), dim3(32,8), 0, stream>>>(hw2, wt2, 128, 12288);
  tconv_kernel<<<dim3(4,4), dim3(32,8), 0, stream>>>(vw1, vw1t, 128, 128);
  tconv_kernel<<<dim3(4,4), dim3(32,8), 0, stream>>>(vw2, vw2t, 128, 128);
  tconv_kernel<<<dim3(4,8), dim3(32,8), 0, stream>>>(aw1, aw1t, 256, 128);
  tconv_kernel<<<dim3(4,4), dim3(32,8), 0, stream>>>(aw2, aw2t, 128, 128);
  k1_hidden<<<512, 256, 0, stream>>>(obs, hw1, hb1, h16);
  k2_hyper<<<256, 512, 0, stream>>>(obs, h16, wt2, hb2, emb16, mean16);
  k4_mlp<<<256, 256, 0, stream>>>(emb16, mean16, vw1t, vw2t, aw1t, aw2t,
                                  vb1, vb2, ab1, ab2, aw3, ab3, outp);
}

// Round 2
// 146.202 us; speedup vs baseline: 1.4001x; 1.4001x over previous
//
#include <hip/hip_runtime.h>

// ---------- types / helpers ----------
typedef _Float16 f16x8 __attribute__((ext_vector_type(8)));
typedef float f32x4 __attribute__((ext_vector_type(4)));

__device__ __forceinline__ float tanh_fast(float x){
  // tanh(x) = 1 - 2/(1+exp2(2*log2e*x)); exact at saturation
  float e = __builtin_amdgcn_exp2f(x * 2.88539008177793f);
  return 1.f - 2.f * __builtin_amdgcn_rcpf(1.f + e);
}
__device__ __forceinline__ unsigned short f2h(float f){
  return __builtin_bit_cast(unsigned short, (_Float16)f);
}
__device__ __forceinline__ float h2f(unsigned short u){
  return (float)__builtin_bit_cast(_Float16, u);
}
__device__ __forceinline__ f32x4 mfma16(f16x8 a, f16x8 b, f32x4 c){
  return __builtin_amdgcn_mfma_f32_16x16x32_f16(a, b, c, 0, 0, 0);
}

// A-fragment from an LDS [32][128] f16 tile.
// MFMA 16x16x32: lane holds A[row=lane&15][k0=8*(lane>>4) + j], j=0..7 (per 32-K step s)
__device__ __forceinline__ f16x8 ldsA(const unsigned short* buf, int rb, int s, int lane){
  return *(const f16x8*)(buf + (rb*16 + (lane&15))*128 + s*32 + ((lane>>4)<<3));
}

// ---------- weight transpose+convert: in f32 [R][C] -> out f16 [C][R] ----------
__global__ void tconv_kernel(const float* __restrict__ in, unsigned short* __restrict__ out,
                             int R, int C){
  __shared__ float t[32][33];
  int c0 = blockIdx.x*32, r0 = blockIdx.y*32;
  int tx = threadIdx.x, ty = threadIdx.y;
  #pragma unroll
  for (int j=ty; j<32; j+=8) t[j][tx] = in[(size_t)(r0+j)*C + c0 + tx];
  __syncthreads();
  #pragma unroll
  for (int j=ty; j<32; j+=8) out[(size_t)(c0+j)*R + r0 + tx] = f2h(t[tx][j]);
}

// ---------- K1: h = tanh(x @ hw1 + hb1), x built from obs; h stored f16 ----------
__global__ __launch_bounds__(256) void k1_hidden(const float* __restrict__ obs,
    const float* __restrict__ hw1, const float* __restrict__ hb1,
    unsigned short* __restrict__ h16){
  __shared__ float w_s[96*128];
  __shared__ float x_s[16*96];
  __shared__ float b_s[128];
  int t = threadIdx.x;
  for (int idx=t; idx<96*128; idx+=256) w_s[idx] = hw1[idx];
  if (t < 128) b_s[t] = hb1[t];
  int n0 = blockIdx.x * 16;
  for (int idx=t; idx<16*96; idx+=256){
    int r = idx/96, i = idx - r*96;
    int n = n0 + r; int b = n>>3, l = n&7;
    x_s[idx] = (i<64) ? obs[b*360 + i] : obs[b*360 + 104 + (l<<5) + (i-64)];
  }
  __syncthreads();
  for (int e=t; e<16*128; e+=256){
    int r = e>>7, o = e&127;
    float acc = b_s[o];
    const float* xr = &x_s[r*96];
    #pragma unroll 4
    for (int i=0;i<96;++i) acc = fmaf(xr[i], w_s[i*128+o], acc);
    h16[(size_t)(n0+r)*128 + o] = f2h(tanh_fast(acc));
  }
}

// ---------- K2: fused hypernet GEMM + tanh + x-contraction + emb/mean ----------
// grid 256 (32 rows each), block 512 (8 waves).
// Wave w owns OUTPUT COLUMNS w*16 .. w*16+15 for all 32 rows, loops ALL 96 i-groups.
// Per-wave state: afrag[2][4] (32 regs) + 2x double-buffered B-frags (32) + facc (8).
__global__ __launch_bounds__(512, 2) void k2_hyper(const float* __restrict__ obs,
    const unsigned short* __restrict__ h16, const unsigned short* __restrict__ wt2,
    const float* __restrict__ hb2,
    unsigned short* __restrict__ emb16, unsigned short* __restrict__ mean16){
  __shared__ float x_s[96*32];     // [i][row] layout: conflict-free reads
  __shared__ float acc_s[32*132];  // padded stride 132
  int t = threadIdx.x;
  int lane = t & 63, w = t >> 6;
  int R0 = blockIdx.x * 32;
  int wcol = w*16 + (lane&15);
  int kof  = (lane>>4) << 3;
  int rloc = (lane>>4) << 2;

  for (int idx=t; idx<96*32; idx+=512){
    int i = idx>>5, r = idx&31;
    int n = R0 + r; int b = n>>3, l = n&7;
    x_s[idx] = (i<64) ? obs[b*360 + i] : obs[b*360 + 104 + (l<<5) + (i-64)];
  }

  // A fragments: rows R0 + rb*16 + (lane&15), all 4 K-steps, from global h16 (f16)
  f16x8 af[2][4];
  #pragma unroll
  for (int rb=0; rb<2; ++rb)
    #pragma unroll
    for (int s=0; s<4; ++s)
      af[rb][s] = *(const f16x8*)(h16 + (size_t)(R0 + rb*16 + (lane&15))*128 + s*32 + kof);

  __syncthreads();

  float fa0[4] = {0.f,0.f,0.f,0.f};
  float fa1[4] = {0.f,0.f,0.f,0.f};

#define K2_LOAD(B0,B1,B2,B3,BIAS,II) do{                                  \
    const unsigned short* wr_ = wt2 + (size_t)((II)*128 + wcol)*128 + kof; \
    B0 = *(const f16x8*)(wr_);                                             \
    B1 = *(const f16x8*)(wr_+32);                                          \
    B2 = *(const f16x8*)(wr_+64);                                          \
    B3 = *(const f16x8*)(wr_+96);                                          \
    BIAS = hb2[(II)*128 + wcol];                                           \
  }while(0)

#define K2_CONSUME(B0,B1,B2,B3,BIAS,II) do{                                \
    f32x4 a0 = {0.f,0.f,0.f,0.f}, a1 = {0.f,0.f,0.f,0.f};                  \
    a0 = mfma16(af[0][0], B0, a0); a1 = mfma16(af[1][0], B0, a1);          \
    a0 = mfma16(af[0][1], B1, a0); a1 = mfma16(af[1][1], B1, a1);          \
    a0 = mfma16(af[0][2], B2, a0); a1 = mfma16(af[1][2], B2, a1);          \
    a0 = mfma16(af[0][3], B3, a0); a1 = mfma16(af[1][3], B3, a1);          \
    _Pragma("unroll")                                                      \
    for (int reg=0; reg<4; ++reg){                                         \
      float t0 = tanh_fast(a0[reg]+(BIAS));                                \
      float t1 = tanh_fast(a1[reg]+(BIAS));                                \
      fa0[reg] = fmaf(x_s[(II)*32 + rloc + reg],      t0, fa0[reg]);       \
      fa1[reg] = fmaf(x_s[(II)*32 + 16 + rloc + reg], t1, fa1[reg]);       \
    }                                                                      \
  }while(0)

  f16x8 bA0,bA1,bA2,bA3, bB0,bB1,bB2,bB3;
  float biasA, biasB;
  K2_LOAD(bA0,bA1,bA2,bA3,biasA,0);
  for (int i=0; i<96; i+=2){
    K2_LOAD(bB0,bB1,bB2,bB3,biasB,i+1);
    K2_CONSUME(bA0,bA1,bA2,bA3,biasA,i);
    if (i+2 < 96) K2_LOAD(bA0,bA1,bA2,bA3,biasA,i+2);
    K2_CONSUME(bB0,bB1,bB2,bB3,biasB,i+1);
  }
#undef K2_LOAD
#undef K2_CONSUME

  // each (row,col) owned by exactly one lane -> plain stores, no atomics
  #pragma unroll
  for (int reg=0; reg<4; ++reg){
    acc_s[(rloc+reg)*132      + wcol] = fa0[reg];
    acc_s[(16+rloc+reg)*132   + wcol] = fa1[reg];
  }
  __syncthreads();

  // emb = tanh(acc); write emb16 (vectorized) and keep tanh'd value for mean
  {
    int r = t>>4, c8 = (t&15)<<3;
    float v[8];
    unsigned short us[8];
    #pragma unroll
    for (int j=0;j<8;++j){
      v[j] = tanh_fast(acc_s[r*132 + c8 + j]);
      us[j] = f2h(v[j]);
      acc_s[r*132 + c8 + j] = v[j];
    }
    *(uint4*)(emb16 + (size_t)(R0+r)*128 + c8) = *(uint4*)us;
  }
  __syncthreads();
  {
    int b_loc = t>>7, o = t&127;   // 4 batches x 128 = 512 = blockDim
    float m = 0.f;
    #pragma unroll
    for (int l=0;l<8;++l) m += acc_s[(b_loc*8+l)*132 + o];
    mean16[(size_t)(R0/8 + b_loc)*128 + o] = f2h(m * 0.125f);
  }
}

// ---------- K4: fused MLP chain + softmax + final ----------
// One GEMM stage: out = tanh(in @ W^T-stored + bias). KS = K/32. Dual A-source for K=256.
template<int KS>
__device__ __forceinline__ void stage(const unsigned short* inA, const unsigned short* inB,
    const unsigned short* wt, const float* bias, unsigned short* outb, int w, int lane){
  #pragma unroll
  for (int obl=0; obl<2; ++obl){
    int col = ((w*2+obl)<<4) + (lane&15);
    f32x4 a0 = {0.f,0.f,0.f,0.f}, a1v = {0.f,0.f,0.f,0.f};
    #pragma unroll
    for (int s=0;s<KS;++s){
      f16x8 bfr = *(const f16x8*)(wt + (size_t)col*(KS*32) + s*32 + ((lane>>4)<<3));
      f16x8 aa0, aa1;
      if (KS==8 && s>=4){ aa0 = ldsA(inB,0,s-4,lane); aa1 = ldsA(inB,1,s-4,lane); }
      else              { aa0 = ldsA(inA,0,s,lane);   aa1 = ldsA(inA,1,s,lane);   }
      a0  = mfma16(aa0, bfr, a0);
      a1v = mfma16(aa1, bfr, a1v);
    }
    float bb = bias[col];
    #pragma unroll
    for (int reg=0;reg<4;++reg){
      int r0 = ((lane>>4)<<2) + reg;
      outb[r0*128 + col]      = f2h(tanh_fast(a0[reg] + bb));
      outb[(16+r0)*128 + col] = f2h(tanh_fast(a1v[reg] + bb));
    }
  }
}

__global__ __launch_bounds__(256) void k4_mlp(
    const unsigned short* __restrict__ emb16, const unsigned short* __restrict__ mean16,
    const unsigned short* __restrict__ vw1t, const unsigned short* __restrict__ vw2t,
    const unsigned short* __restrict__ aw1t, const unsigned short* __restrict__ aw2t,
    const float* __restrict__ vb1, const float* __restrict__ vb2,
    const float* __restrict__ ab1, const float* __restrict__ ab2,
    const float* __restrict__ aw3, const float* __restrict__ ab3,
    float* __restrict__ outp){
  __shared__ unsigned short bufE[32*128];
  __shared__ unsigned short bufM[32*128];
  __shared__ unsigned short bufA[32*128];
  __shared__ float fin[4*128];
  __shared__ float lp[32*8];
  __shared__ float att_s[32];
  int t = threadIdx.x, lane = t&63, w = t>>6;
  int R0 = blockIdx.x*32;

  for (int idx=t; idx<512; idx+=256){
    int r = idx>>4, c8 = (idx&15)<<3;
    int n = R0 + r;
    *(uint4*)(bufE + r*128 + c8) = *(const uint4*)(emb16  + (size_t)n*128 + c8);
    *(uint4*)(bufM + r*128 + c8) = *(const uint4*)(mean16 + (size_t)(n & 1023)*128 + c8); // mean[n % 1024]!
  }
  for (int idx=t; idx<512; idx+=256) fin[idx] = 0.f;
  __syncthreads();

  stage<8>(bufE, bufM, aw1t, ab1, bufA, w, lane);   // a1 = tanh([emb|mean] @ aw1 + ab1)
  __syncthreads();
  stage<4>(bufA, nullptr, aw2t, ab2, bufM, w, lane); // a2
  __syncthreads();
  {
    int r = t>>3, seg = t&7;
    float p = 0.f;
    const unsigned short* row = bufM + r*128 + seg*16;
    const float* w3 = aw3 + seg*16;
    #pragma unroll
    for (int k=0;k<16;++k) p += h2f(row[k]) * w3[k];
    lp[r*8+seg] = p;
  }
  __syncthreads();
  if (t < 4){   // per-batch softmax over 8 landmarks
    float lg[8]; float mx = -1e30f;
    for (int l=0;l<8;++l){
      float s = ab3[0];
      #pragma unroll
      for (int sg=0;sg<8;++sg) s += lp[(t*8+l)*8+sg];
      lg[l] = s; mx = fmaxf(mx, s);
    }
    float sum = 0.f;
    for (int l=0;l<8;++l){ lg[l] = __builtin_amdgcn_exp2f((lg[l]-mx)*1.44269504089f); sum += lg[l]; }
    float inv = __builtin_amdgcn_rcpf(sum);
    for (int l=0;l<8;++l) att_s[t*8+l] = lg[l]*inv;
  }
  __syncthreads();
  stage<4>(bufE, nullptr, vw1t, vb1, bufA, w, lane); // v1
  __syncthreads();
  { // v2 + final weighted accumulation
    #pragma unroll
    for (int obl=0; obl<2; ++obl){
      int col = ((w*2+obl)<<4) + (lane&15);
      f32x4 a0 = {0.f,0.f,0.f,0.f}, a1v = {0.f,0.f,0.f,0.f};
      #pragma unroll
      for (int s=0;s<4;++s){
        f16x8 bfr = *(const f16x8*)(vw2t + (size_t)col*128 + s*32 + ((lane>>4)<<3));
        a0  = mfma16(ldsA(bufA,0,s,lane), bfr, a0);
        a1v = mfma16(ldsA(bufA,1,s,lane), bfr, a1v);
      }
      float bb = vb2[col];
      #pragma unroll
      for (int reg=0;reg<4;++reg){
        int r0 = ((lane>>4)<<2) + reg;
        float v0 = tanh_fast(a0[reg]+bb);
        float v1 = tanh_fast(a1v[reg]+bb);
        atomicAdd(&fin[((r0)>>3)*128 + col],    att_s[r0]    * v0);
        atomicAdd(&fin[((16+r0)>>3)*128 + col], att_s[16+r0] * v1);
      }
    }
  }
  __syncthreads();
  for (int idx=t; idx<512; idx+=256){
    int b_loc = idx>>7, o = idx&127;
    outp[(size_t)(R0/8 + b_loc)*128 + o] = fin[idx];
  }
}

// ---------- launch ----------
extern "C" void kernel_launch(void* const* d_in, const int* in_sizes, int n_in,
                              void* d_out, int out_size, void* d_ws, size_t ws_size,
                              hipStream_t stream){
  const float* obs = (const float*)d_in[0];
  const float* hw1 = (const float*)d_in[3];
  const float* hb1 = (const float*)d_in[4];
  const float* hw2 = (const float*)d_in[5];
  const float* hb2 = (const float*)d_in[6];
  const float* vw1 = (const float*)d_in[7];
  const float* vb1 = (const float*)d_in[8];
  const float* vw2 = (const float*)d_in[9];
  const float* vb2 = (const float*)d_in[10];
  const float* aw1 = (const float*)d_in[11];
  const float* ab1 = (const float*)d_in[12];
  const float* aw2 = (const float*)d_in[13];
  const float* ab2 = (const float*)d_in[14];
  const float* aw3 = (const float*)d_in[15];
  const float* ab3 = (const float*)d_in[16];

  char* ws = (char*)d_ws;
  unsigned short* wt2    = (unsigned short*)(ws);             // 12288*128*2 = 3,145,728
  unsigned short* h16    = (unsigned short*)(ws + 3145728);   // 8192*128*2  = 2,097,152
  unsigned short* emb16  = (unsigned short*)(ws + 5242880);   // 2,097,152
  unsigned short* mean16 = (unsigned short*)(ws + 7340032);   // 1024*128*2  = 262,144
  unsigned short* vw1t   = (unsigned short*)(ws + 7602176);   // 32,768
  unsigned short* vw2t   = (unsigned short*)(ws + 7634944);   // 32,768
  unsigned short* aw1t   = (unsigned short*)(ws + 7667712);   // 65,536
  unsigned short* aw2t   = (unsigned short*)(ws + 7733248);   // 32,768   (end 7,766,016 B)
  float* outp = (float*)d_out;

  tconv_kernel<<<dim3(12288/32, 128/32), dim3(32,8), 0, stream>>>(hw2, wt2, 128, 12288);
  tconv_kernel<<<dim3(4,4), dim3(32,8), 0, stream>>>(vw1, vw1t, 128, 128);
  tconv_kernel<<<dim3(4,4), dim3(32,8), 0, stream>>>(vw2, vw2t, 128, 128);
  tconv_kernel<<<dim3(4,8), dim3(32,8), 0, stream>>>(aw1, aw1t, 256, 128);
  tconv_kernel<<<dim3(4,4), dim3(32,8), 0, stream>>>(aw2, aw2t, 128, 128);
  k1_hidden<<<512, 256, 0, stream>>>(obs, hw1, hb1, h16);
  k2_hyper<<<256, 512, 0, stream>>>(obs, h16, wt2, hb2, emb16, mean16);
  k4_mlp<<<256, 256, 0, stream>>>(emb16, mean16, vw1t, vw2t, aw1t, aw2t,
                                  vb1, vb2, ab1, ab2, aw3, ab3, outp);
}

// Round 3
// 141.854 us; speedup vs baseline: 1.4430x; 1.0306x over previous
//
#include <hip/hip_runtime.h>

// ---------- types / helpers ----------
typedef _Float16 f16x8 __attribute__((ext_vector_type(8)));
typedef float f32x4 __attribute__((ext_vector_type(4)));

__device__ __forceinline__ float tanh_fast(float x){
  // tanh(x) = 1 - 2/(1+exp2(2*log2e*x)); exact at saturation
  float e = __builtin_amdgcn_exp2f(x * 2.88539008177793f);
  return 1.f - 2.f * __builtin_amdgcn_rcpf(1.f + e);
}
__device__ __forceinline__ unsigned short f2h(float f){
  return __builtin_bit_cast(unsigned short, (_Float16)f);
}
__device__ __forceinline__ float h2f(unsigned short u){
  return (float)__builtin_bit_cast(_Float16, u);
}
__device__ __forceinline__ f32x4 mfma16(f16x8 a, f16x8 b, f32x4 c){
  return __builtin_amdgcn_mfma_f32_16x16x32_f16(a, b, c, 0, 0, 0);
}

// A-fragment from an LDS [32][128] f16 tile.
__device__ __forceinline__ f16x8 ldsA(const unsigned short* buf, int rb, int s, int lane){
  return *(const f16x8*)(buf + (rb*16 + (lane&15))*128 + s*32 + ((lane>>4)<<3));
}

// ---------- PREP: all 5 weight transposes + k1 hidden, one launch ----------
// blocks [0,1536): hw2 tconv; [1536,1552) vw1; [1552,1568) vw2; [1568,1600) aw1;
// [1600,1616) aw2; [1616,2128): k1 (512 blocks x 16 rows)
__global__ __launch_bounds__(256) void prep_kernel(
    const float* __restrict__ obs, const float* __restrict__ hw1,
    const float* __restrict__ hb1, const float* __restrict__ hw2,
    const float* __restrict__ vw1, const float* __restrict__ vw2,
    const float* __restrict__ aw1, const float* __restrict__ aw2,
    unsigned short* __restrict__ wt2, unsigned short* __restrict__ vw1t,
    unsigned short* __restrict__ vw2t, unsigned short* __restrict__ aw1t,
    unsigned short* __restrict__ aw2t, unsigned short* __restrict__ h16){
  int b = blockIdx.x, t = threadIdx.x;
  if (b < 1616){
    __shared__ float tile[32][33];
    const float* in; unsigned short* out; int R, C, bx, by;
    if (b < 1536)      { in=hw2; out=wt2;  R=128; C=12288; bx=b%384;      by=b/384; }
    else if (b < 1552) { int q=b-1536; in=vw1; out=vw1t; R=128; C=128; bx=q&3; by=q>>2; }
    else if (b < 1568) { int q=b-1552; in=vw2; out=vw2t; R=128; C=128; bx=q&3; by=q>>2; }
    else if (b < 1600) { int q=b-1568; in=aw1; out=aw1t; R=256; C=128; bx=q&3; by=q>>2; }
    else               { int q=b-1600; in=aw2; out=aw2t; R=128; C=128; bx=q&3; by=q>>2; }
    int c0=bx*32, r0=by*32, tx=t&31, ty=t>>5;
    #pragma unroll
    for (int j=ty; j<32; j+=8) tile[j][tx] = in[(size_t)(r0+j)*C + c0 + tx];
    __syncthreads();
    #pragma unroll
    for (int j=ty; j<32; j+=8) out[(size_t)(c0+j)*R + r0 + tx] = f2h(tile[tx][j]);
  } else {
    __shared__ float w_s[96*128];
    __shared__ float x_s[16*96];
    __shared__ float b_s[128];
    int n0 = (b-1616)*16;
    for (int idx=t; idx<96*128; idx+=256) w_s[idx] = hw1[idx];
    if (t < 128) b_s[t] = hb1[t];
    for (int idx=t; idx<16*96; idx+=256){
      int r = idx/96, i = idx - r*96;
      int n = n0 + r; int bb = n>>3, l = n&7;
      x_s[idx] = (i<64) ? obs[bb*360 + i] : obs[bb*360 + 104 + (l<<5) + (i-64)];
    }
    __syncthreads();
    for (int e=t; e<16*128; e+=256){
      int r = e>>7, o = e&127;
      float acc = b_s[o];
      const float* xr = &x_s[r*96];
      #pragma unroll 4
      for (int i=0;i<96;++i) acc = fmaf(xr[i], w_s[i*128+o], acc);
      h16[(size_t)(n0+r)*128 + o] = f2h(tanh_fast(acc));
    }
  }
}

// ---------- K2: fused hypernet GEMM + tanh + x-contraction (i-split) ----------
// grid 512: blockIdx = (rowTile<<1)|iHalf. 32 rows, i in [iHalf*48, +48).
// 8 waves own 16 output cols each; partial sums atomicAdd'ed into global f32 acc.
__global__ __launch_bounds__(512, 4) void k2_hyper(const float* __restrict__ obs,
    const unsigned short* __restrict__ h16, const unsigned short* __restrict__ wt2,
    const float* __restrict__ hb2, float* __restrict__ accg){
  __shared__ float x_s[48*32];   // [i_local][row]
  int t = threadIdx.x, lane = t & 63, w = t >> 6;
  int rt = blockIdx.x >> 1, ih = blockIdx.x & 1;
  int R0 = rt*32, ibase = ih*48;
  int wcol = w*16 + (lane&15);
  int kof  = (lane>>4) << 3;
  int rloc = (lane>>4) << 2;

  for (int idx=t; idx<48*32; idx+=512){
    int il = idx>>5, r = idx&31;
    int i = ibase + il;
    int n = R0 + r; int bb = n>>3, l = n&7;
    x_s[idx] = (i<64) ? obs[bb*360 + i] : obs[bb*360 + 104 + (l<<5) + (i-64)];
  }

  f16x8 af[2][4];
  #pragma unroll
  for (int rb=0; rb<2; ++rb)
    #pragma unroll
    for (int s=0; s<4; ++s)
      af[rb][s] = *(const f16x8*)(h16 + (size_t)(R0 + rb*16 + (lane&15))*128 + s*32 + kof);

  __syncthreads();

  float fa0[4] = {0.f,0.f,0.f,0.f};
  float fa1[4] = {0.f,0.f,0.f,0.f};
  const unsigned short* wp = wt2 + (size_t)(ibase*128 + wcol)*128 + kof;
  const float* bp = hb2 + ibase*128 + wcol;

  f16x8 A0,A1,A2,A3, B0,B1,B2,B3;
  float biasA, biasB;

#define K2L(X0,X1,X2,X3,BI) do{                 \
    X0 = *(const f16x8*)(wp);                   \
    X1 = *(const f16x8*)(wp+32);                \
    X2 = *(const f16x8*)(wp+64);                \
    X3 = *(const f16x8*)(wp+96);                \
    BI = *bp;                                   \
    wp += 16384; bp += 128;                     \
  }while(0)

#define K2C(X0,X1,X2,X3,BI,IL) do{                                   \
    f32x4 a0 = {BI,BI,BI,BI}, a1 = {BI,BI,BI,BI};                    \
    a0 = mfma16(af[0][0], X0, a0); a1 = mfma16(af[1][0], X0, a1);    \
    a0 = mfma16(af[0][1], X1, a0); a1 = mfma16(af[1][1], X1, a1);    \
    a0 = mfma16(af[0][2], X2, a0); a1 = mfma16(af[1][2], X2, a1);    \
    a0 = mfma16(af[0][3], X3, a0); a1 = mfma16(af[1][3], X3, a1);    \
    _Pragma("unroll")                                                \
    for (int reg=0; reg<4; ++reg){                                   \
      fa0[reg] = fmaf(x_s[(IL)*32 + rloc + reg],      tanh_fast(a0[reg]), fa0[reg]); \
      fa1[reg] = fmaf(x_s[(IL)*32 + 16 + rloc + reg], tanh_fast(a1[reg]), fa1[reg]); \
    }                                                                \
  }while(0)

  K2L(A0,A1,A2,A3,biasA);
  K2L(B0,B1,B2,B3,biasB);
  for (int il=0; il<46; il+=2){
    K2C(A0,A1,A2,A3,biasA,il);
    K2L(A0,A1,A2,A3,biasA);
    K2C(B0,B1,B2,B3,biasB,il+1);
    K2L(B0,B1,B2,B3,biasB);
  }
  K2C(A0,A1,A2,A3,biasA,46);
  K2C(B0,B1,B2,B3,biasB,47);
#undef K2L
#undef K2C

  #pragma unroll
  for (int reg=0; reg<4; ++reg){
    atomicAdd(&accg[(size_t)(R0 + rloc + reg)*128 + wcol],      fa0[reg]);
    atomicAdd(&accg[(size_t)(R0 + 16 + rloc + reg)*128 + wcol], fa1[reg]);
  }
}

// ---------- K3: finalize emb = tanh(acc), mean over landmarks ----------
__global__ __launch_bounds__(256) void k3_finish(const float* __restrict__ accg,
    unsigned short* __restrict__ emb16, unsigned short* __restrict__ mean16){
  int t = threadIdx.x, R0 = blockIdx.x*32;
  for (int task=t; task<512; task+=256){
    int bl = task>>7, o = task&127;
    float m = 0.f;
    #pragma unroll
    for (int l=0;l<8;++l){
      float e = tanh_fast(accg[(size_t)(R0 + bl*8 + l)*128 + o]);
      emb16[(size_t)(R0 + bl*8 + l)*128 + o] = f2h(e);
      m += e;
    }
    mean16[(size_t)(R0/8 + bl)*128 + o] = f2h(m * 0.125f);
  }
}

// ---------- K4: fused MLP chain + softmax + final ----------
template<int KS>
__device__ __forceinline__ void stage(const unsigned short* inA, const unsigned short* inB,
    const unsigned short* wt, const float* bias, unsigned short* outb, int w, int lane){
  #pragma unroll
  for (int obl=0; obl<2; ++obl){
    int col = ((w*2+obl)<<4) + (lane&15);
    f32x4 a0 = {0.f,0.f,0.f,0.f}, a1v = {0.f,0.f,0.f,0.f};
    #pragma unroll
    for (int s=0;s<KS;++s){
      f16x8 bfr = *(const f16x8*)(wt + (size_t)col*(KS*32) + s*32 + ((lane>>4)<<3));
      f16x8 aa0, aa1;
      if (KS==8 && s>=4){ aa0 = ldsA(inB,0,s-4,lane); aa1 = ldsA(inB,1,s-4,lane); }
      else              { aa0 = ldsA(inA,0,s,lane);   aa1 = ldsA(inA,1,s,lane);   }
      a0  = mfma16(aa0, bfr, a0);
      a1v = mfma16(aa1, bfr, a1v);
    }
    float bb = bias[col];
    #pragma unroll
    for (int reg=0;reg<4;++reg){
      int r0 = ((lane>>4)<<2) + reg;
      outb[r0*128 + col]      = f2h(tanh_fast(a0[reg] + bb));
      outb[(16+r0)*128 + col] = f2h(tanh_fast(a1v[reg] + bb));
    }
  }
}

__global__ __launch_bounds__(256) void k4_mlp(
    const unsigned short* __restrict__ emb16, const unsigned short* __restrict__ mean16,
    const unsigned short* __restrict__ vw1t, const unsigned short* __restrict__ vw2t,
    const unsigned short* __restrict__ aw1t, const unsigned short* __restrict__ aw2t,
    const float* __restrict__ vb1, const float* __restrict__ vb2,
    const float* __restrict__ ab1, const float* __restrict__ ab2,
    const float* __restrict__ aw3, const float* __restrict__ ab3,
    float* __restrict__ outp){
  __shared__ unsigned short bufE[32*128];
  __shared__ unsigned short bufM[32*128];
  __shared__ unsigned short bufA[32*128];
  __shared__ float fin[4*128];
  __shared__ float lp[32*8];
  __shared__ float att_s[32];
  int t = threadIdx.x, lane = t&63, w = t>>6;
  int R0 = blockIdx.x*32;

  for (int idx=t; idx<512; idx+=256){
    int r = idx>>4, c8 = (idx&15)<<3;
    int n = R0 + r;
    *(uint4*)(bufE + r*128 + c8) = *(const uint4*)(emb16  + (size_t)n*128 + c8);
    *(uint4*)(bufM + r*128 + c8) = *(const uint4*)(mean16 + (size_t)(n & 1023)*128 + c8); // mean[n % 1024]!
  }
  for (int idx=t; idx<512; idx+=256) fin[idx] = 0.f;
  __syncthreads();

  stage<8>(bufE, bufM, aw1t, ab1, bufA, w, lane);
  __syncthreads();
  stage<4>(bufA, nullptr, aw2t, ab2, bufM, w, lane);
  __syncthreads();
  {
    int r = t>>3, seg = t&7;
    float p = 0.f;
    const unsigned short* row = bufM + r*128 + seg*16;
    const float* w3 = aw3 + seg*16;
    #pragma unroll
    for (int k=0;k<16;++k) p += h2f(row[k]) * w3[k];
    lp[r*8+seg] = p;
  }
  __syncthreads();
  if (t < 4){
    float lg[8]; float mx = -1e30f;
    for (int l=0;l<8;++l){
      float s = ab3[0];
      #pragma unroll
      for (int sg=0;sg<8;++sg) s += lp[(t*8+l)*8+sg];
      lg[l] = s; mx = fmaxf(mx, s);
    }
    float sum = 0.f;
    for (int l=0;l<8;++l){ lg[l] = __builtin_amdgcn_exp2f((lg[l]-mx)*1.44269504089f); sum += lg[l]; }
    float inv = __builtin_amdgcn_rcpf(sum);
    for (int l=0;l<8;++l) att_s[t*8+l] = lg[l]*inv;
  }
  __syncthreads();
  stage<4>(bufE, nullptr, vw1t, vb1, bufA, w, lane);
  __syncthreads();
  {
    #pragma unroll
    for (int obl=0; obl<2; ++obl){
      int col = ((w*2+obl)<<4) + (lane&15);
      f32x4 a0 = {0.f,0.f,0.f,0.f}, a1v = {0.f,0.f,0.f,0.f};
      #pragma unroll
      for (int s=0;s<4;++s){
        f16x8 bfr = *(const f16x8*)(vw2t + (size_t)col*128 + s*32 + ((lane>>4)<<3));
        a0  = mfma16(ldsA(bufA,0,s,lane), bfr, a0);
        a1v = mfma16(ldsA(bufA,1,s,lane), bfr, a1v);
      }
      float bb = vb2[col];
      #pragma unroll
      for (int reg=0;reg<4;++reg){
        int r0 = ((lane>>4)<<2) + reg;
        float v0 = tanh_fast(a0[reg]+bb);
        float v1 = tanh_fast(a1v[reg]+bb);
        atomicAdd(&fin[((r0)>>3)*128 + col],    att_s[r0]    * v0);
        atomicAdd(&fin[((16+r0)>>3)*128 + col], att_s[16+r0] * v1);
      }
    }
  }
  __syncthreads();
  for (int idx=t; idx<512; idx+=256){
    int b_loc = idx>>7, o = idx&127;
    outp[(size_t)(R0/8 + b_loc)*128 + o] = fin[idx];
  }
}

// ---------- launch ----------
extern "C" void kernel_launch(void* const* d_in, const int* in_sizes, int n_in,
                              void* d_out, int out_size, void* d_ws, size_t ws_size,
                              hipStream_t stream){
  const float* obs = (const float*)d_in[0];
  const float* hw1 = (const float*)d_in[3];
  const float* hb1 = (const float*)d_in[4];
  const float* hw2 = (const float*)d_in[5];
  const float* hb2 = (const float*)d_in[6];
  const float* vw1 = (const float*)d_in[7];
  const float* vb1 = (const float*)d_in[8];
  const float* vw2 = (const float*)d_in[9];
  const float* vb2 = (const float*)d_in[10];
  const float* aw1 = (const float*)d_in[11];
  const float* ab1 = (const float*)d_in[12];
  const float* aw2 = (const float*)d_in[13];
  const float* ab2 = (const float*)d_in[14];
  const float* aw3 = (const float*)d_in[15];
  const float* ab3 = (const float*)d_in[16];

  char* ws = (char*)d_ws;
  // wt2 region [0, 3145728) is reused by emb16+mean16 after k2 (lifetimes disjoint)
  unsigned short* wt2    = (unsigned short*)(ws);             // 3,145,728 B
  unsigned short* emb16  = (unsigned short*)(ws);             // 2,097,152 B (alias, after k2)
  unsigned short* mean16 = (unsigned short*)(ws + 2097152);   //   262,144 B (alias, after k2)
  unsigned short* h16    = (unsigned short*)(ws + 3145728);   // 2,097,152 B
  float*          accg   = (float*)        (ws + 5242880);    // 4,194,304 B
  unsigned short* vw1t   = (unsigned short*)(ws + 9437184);   //    32,768 B
  unsigned short* vw2t   = (unsigned short*)(ws + 9469952);   //    32,768 B
  unsigned short* aw1t   = (unsigned short*)(ws + 9502720);   //    65,536 B
  unsigned short* aw2t   = (unsigned short*)(ws + 9568256);   //    32,768 B  (end 9,601,024)
  float* outp = (float*)d_out;

  hipMemsetAsync(accg, 0, 8192*128*sizeof(float), stream);
  prep_kernel<<<2128, 256, 0, stream>>>(obs, hw1, hb1, hw2, vw1, vw2, aw1, aw2,
                                        wt2, vw1t, vw2t, aw1t, aw2t, h16);
  k2_hyper<<<512, 512, 0, stream>>>(obs, h16, wt2, hb2, accg);
  k3_finish<<<256, 256, 0, stream>>>(accg, emb16, mean16);
  k4_mlp<<<256, 256, 0, stream>>>(emb16, mean16, vw1t, vw2t, aw1t, aw2t,
                                  vb1, vb2, ab1, ab2, aw3, ab3, outp);
}

// Round 5
// 120.483 us; speedup vs baseline: 1.6990x; 1.1774x over previous
//
#include <hip/hip_runtime.h>

// ---------- types / helpers ----------
typedef _Float16 f16x8 __attribute__((ext_vector_type(8)));
typedef float f32x4 __attribute__((ext_vector_type(4)));

__device__ __forceinline__ float tanh_fast(float x){
  // tanh(x) = 1 - 2/(1+exp2(2*log2e*x)); exact at saturation
  float e = __builtin_amdgcn_exp2f(x * 2.88539008177793f);
  return 1.f - 2.f * __builtin_amdgcn_rcpf(1.f + e);
}
__device__ __forceinline__ unsigned short f2h(float f){
  return __builtin_bit_cast(unsigned short, (_Float16)f);
}
__device__ __forceinline__ float h2f(unsigned short u){
  return (float)__builtin_bit_cast(_Float16, u);
}
__device__ __forceinline__ f32x4 mfma16(f16x8 a, f16x8 b, f32x4 c){
  return __builtin_amdgcn_mfma_f32_16x16x32_f16(a, b, c, 0, 0, 0);
}

// A-fragment from an LDS [32][128] f16 tile.
__device__ __forceinline__ f16x8 ldsA(const unsigned short* buf, int rb, int s, int lane){
  return *(const f16x8*)(buf + (rb*16 + (lane&15))*128 + s*32 + ((lane>>4)<<3));
}

// ---------- PREP: all 5 weight transposes + k1 hidden, one launch ----------
__global__ __launch_bounds__(256) void prep_kernel(
    const float* __restrict__ obs, const float* __restrict__ hw1,
    const float* __restrict__ hb1, const float* __restrict__ hw2,
    const float* __restrict__ vw1, const float* __restrict__ vw2,
    const float* __restrict__ aw1, const float* __restrict__ aw2,
    unsigned short* __restrict__ wt2, unsigned short* __restrict__ vw1t,
    unsigned short* __restrict__ vw2t, unsigned short* __restrict__ aw1t,
    unsigned short* __restrict__ aw2t, unsigned short* __restrict__ h16){
  int b = blockIdx.x, t = threadIdx.x;
  if (b < 1616){
    __shared__ float tile[32][33];
    const float* in; unsigned short* out; int R, C, bx, by;
    if (b < 1536)      { in=hw2; out=wt2;  R=128; C=12288; bx=b%384;      by=b/384; }
    else if (b < 1552) { int q=b-1536; in=vw1; out=vw1t; R=128; C=128; bx=q&3; by=q>>2; }
    else if (b < 1568) { int q=b-1552; in=vw2; out=vw2t; R=128; C=128; bx=q&3; by=q>>2; }
    else if (b < 1600) { int q=b-1568; in=aw1; out=aw1t; R=256; C=128; bx=q&3; by=q>>2; }
    else               { int q=b-1600; in=aw2; out=aw2t; R=128; C=128; bx=q&3; by=q>>2; }
    int c0=bx*32, r0=by*32, tx=t&31, ty=t>>5;
    #pragma unroll
    for (int j=ty; j<32; j+=8) tile[j][tx] = in[(size_t)(r0+j)*C + c0 + tx];
    __syncthreads();
    #pragma unroll
    for (int j=ty; j<32; j+=8) out[(size_t)(c0+j)*R + r0 + tx] = f2h(tile[tx][j]);
  } else {
    __shared__ float w_s[96*128];
    __shared__ float x_s[16*96];
    __shared__ float b_s[128];
    int n0 = (b-1616)*16;
    for (int idx=t; idx<96*128; idx+=256) w_s[idx] = hw1[idx];
    if (t < 128) b_s[t] = hb1[t];
    for (int idx=t; idx<16*96; idx+=256){
      int r = idx/96, i = idx - r*96;
      int n = n0 + r; int bb = n>>3, l = n&7;
      x_s[idx] = (i<64) ? obs[bb*360 + i] : obs[bb*360 + 104 + (l<<5) + (i-64)];
    }
    __syncthreads();
    for (int e=t; e<16*128; e+=256){
      int r = e>>7, o = e&127;
      float acc = b_s[o];
      const float* xr = &x_s[r*96];
      #pragma unroll 4
      for (int i=0;i<96;++i) acc = fmaf(xr[i], w_s[i*128+o], acc);
      h16[(size_t)(n0+r)*128 + o] = f2h(tanh_fast(acc));
    }
  }
}

// ---------- K2: fused hypernet GEMM + tanh + x-contraction ----------
// grid 256: blockIdx = rowTile*4 + iQuarter. 128 rows/block, i in [iq*24, +24).
// 8 waves own 16 output cols each for ALL 8 row-blocks; wt2 read once per 128 rows.
__global__ __launch_bounds__(512, 2) void k2_hyper(const float* __restrict__ obs,
    const unsigned short* __restrict__ h16, const unsigned short* __restrict__ wt2,
    const float* __restrict__ hb2, float* __restrict__ accg){
  __shared__ float x_s[24*128];   // [i_local][row]
  int t = threadIdx.x, lane = t & 63, w = t >> 6;
  int rt = blockIdx.x >> 2, iq = blockIdx.x & 3;
  int R0 = rt*128, ibase = iq*24;
  int wcol = w*16 + (lane&15);
  int kof  = (lane>>4) << 3;
  int rloc = (lane>>4) << 2;

  for (int idx=t; idx<24*128; idx+=512){
    int il = idx>>7, r = idx&127;
    int i = ibase + il;
    int n = R0 + r; int bb = n>>3, l = n&7;
    x_s[idx] = (i<64) ? obs[bb*360 + i] : obs[bb*360 + 104 + (l<<5) + (i-64)];
  }

  // A fragments for 8 row-blocks of 16 rows (i-invariant, held in registers)
  f16x8 af[8][4];
  #pragma unroll
  for (int rb=0; rb<8; ++rb)
    #pragma unroll
    for (int s=0; s<4; ++s)
      af[rb][s] = *(const f16x8*)(h16 + (size_t)(R0 + rb*16 + (lane&15))*128 + s*32 + kof);

  __syncthreads();

  float facc[8][4];
  #pragma unroll
  for (int rb=0;rb<8;++rb)
    #pragma unroll
    for (int reg=0;reg<4;++reg) facc[rb][reg] = 0.f;

  const unsigned short* wp = wt2 + (size_t)(ibase*128 + wcol)*128 + kof;
  const float* bp = hb2 + ibase*128 + wcol;

  f16x8 A0,A1,A2,A3, B0,B1,B2,B3;
  float biasA, biasB;

#define K2L(X0,X1,X2,X3,BI) do{                 \
    X0 = *(const f16x8*)(wp);                   \
    X1 = *(const f16x8*)(wp+32);                \
    X2 = *(const f16x8*)(wp+64);                \
    X3 = *(const f16x8*)(wp+96);                \
    BI = *bp;                                   \
    wp += 16384; bp += 128;                     \
  }while(0)

#define K2C(X0,X1,X2,X3,BI,IL) do{                                       \
    _Pragma("unroll")                                                    \
    for (int rb=0; rb<8; rb+=2){                                         \
      f32x4 a0 = {BI,BI,BI,BI}, a1 = {BI,BI,BI,BI};                      \
      a0 = mfma16(af[rb][0], X0, a0); a1 = mfma16(af[rb+1][0], X0, a1);  \
      a0 = mfma16(af[rb][1], X1, a0); a1 = mfma16(af[rb+1][1], X1, a1);  \
      a0 = mfma16(af[rb][2], X2, a0); a1 = mfma16(af[rb+1][2], X2, a1);  \
      a0 = mfma16(af[rb][3], X3, a0); a1 = mfma16(af[rb+1][3], X3, a1);  \
      f32x4 x0 = *(const f32x4*)(x_s + (IL)*128 + rb*16 + rloc);         \
      f32x4 x1 = *(const f32x4*)(x_s + (IL)*128 + (rb+1)*16 + rloc);     \
      _Pragma("unroll")                                                  \
      for (int reg=0; reg<4; ++reg){                                     \
        facc[rb][reg]   = fmaf(x0[reg], tanh_fast(a0[reg]), facc[rb][reg]);   \
        facc[rb+1][reg] = fmaf(x1[reg], tanh_fast(a1[reg]), facc[rb+1][reg]); \
      }                                                                  \
    }                                                                    \
  }while(0)

  K2L(A0,A1,A2,A3,biasA);
  K2L(B0,B1,B2,B3,biasB);
  for (int il=0; il<22; il+=2){
    K2C(A0,A1,A2,A3,biasA,il);
    K2L(A0,A1,A2,A3,biasA);
    K2C(B0,B1,B2,B3,biasB,il+1);
    K2L(B0,B1,B2,B3,biasB);
  }
  K2C(A0,A1,A2,A3,biasA,22);
  K2C(B0,B1,B2,B3,biasB,23);
#undef K2L
#undef K2C

  #pragma unroll
  for (int rb=0; rb<8; ++rb)
    #pragma unroll
    for (int reg=0; reg<4; ++reg)
      atomicAdd(&accg[(size_t)(R0 + rb*16 + rloc + reg)*128 + wcol], facc[rb][reg]);
}

// ---------- K3: per-batch landmark mean of tanh(accg) -> mean16 ----------
// block b: batches b*4 .. b*4+3
__global__ __launch_bounds__(256) void k3_mean(const float* __restrict__ accg,
    unsigned short* __restrict__ mean16){
  int t = threadIdx.x, B0 = blockIdx.x*4;
  for (int task=t; task<512; task+=256){
    int bl = task>>7, o = task&127;
    float m = 0.f;
    #pragma unroll
    for (int l=0;l<8;++l)
      m += tanh_fast(accg[(size_t)((B0 + bl)*8 + l)*128 + o]);
    mean16[(size_t)(B0 + bl)*128 + o] = f2h(m * 0.125f);
  }
}

// ---------- K4: emb from accg + fused MLP chain + softmax + final ----------
template<int KS>
__device__ __forceinline__ void stage(const unsigned short* inA, const unsigned short* inB,
    const unsigned short* wt, const float* bias, unsigned short* outb, int w, int lane){
  #pragma unroll
  for (int obl=0; obl<2; ++obl){
    int col = ((w*2+obl)<<4) + (lane&15);
    f32x4 a0 = {0.f,0.f,0.f,0.f}, a1v = {0.f,0.f,0.f,0.f};
    #pragma unroll
    for (int s=0;s<KS;++s){
      f16x8 bfr = *(const f16x8*)(wt + (size_t)col*(KS*32) + s*32 + ((lane>>4)<<3));
      f16x8 aa0, aa1;
      if (KS==8 && s>=4){ aa0 = ldsA(inB,0,s-4,lane); aa1 = ldsA(inB,1,s-4,lane); }
      else              { aa0 = ldsA(inA,0,s,lane);   aa1 = ldsA(inA,1,s,lane);   }
      a0  = mfma16(aa0, bfr, a0);
      a1v = mfma16(aa1, bfr, a1v);
    }
    float bb = bias[col];
    #pragma unroll
    for (int reg=0;reg<4;++reg){
      int r0 = ((lane>>4)<<2) + reg;
      outb[r0*128 + col]      = f2h(tanh_fast(a0[reg] + bb));
      outb[(16+r0)*128 + col] = f2h(tanh_fast(a1v[reg] + bb));
    }
  }
}

__global__ __launch_bounds__(256) void k4_mlp(
    const float* __restrict__ accg, const unsigned short* __restrict__ mean16,
    const unsigned short* __restrict__ vw1t, const unsigned short* __restrict__ vw2t,
    const unsigned short* __restrict__ aw1t, const unsigned short* __restrict__ aw2t,
    const float* __restrict__ vb1, const float* __restrict__ vb2,
    const float* __restrict__ ab1, const float* __restrict__ ab2,
    const float* __restrict__ aw3, const float* __restrict__ ab3,
    float* __restrict__ outp){
  __shared__ unsigned short bufE[32*128];
  __shared__ unsigned short bufM[32*128];
  __shared__ unsigned short bufA[32*128];
  __shared__ float fin[4*128];
  __shared__ float lp[32*8];
  __shared__ float att_s[32];
  int t = threadIdx.x, lane = t&63, w = t>>6;
  int R0 = blockIdx.x*32;

  // emb = tanh(accg) for our 32 rows
  for (int idx=t; idx<4096; idx+=256)
    bufE[idx] = f2h(tanh_fast(accg[(size_t)R0*128 + idx]));
  // mean_rep faithful ordering: row n pairs with mean[(n % 1024)]
  for (int idx=t; idx<512; idx+=256){
    int r = idx>>4, c8 = (idx&15)<<3;
    int n = R0 + r;
    *(uint4*)(bufM + r*128 + c8) = *(const uint4*)(mean16 + (size_t)(n & 1023)*128 + c8);
  }
  for (int idx=t; idx<512; idx+=256) fin[idx] = 0.f;
  __syncthreads();

  stage<8>(bufE, bufM, aw1t, ab1, bufA, w, lane);
  __syncthreads();
  stage<4>(bufA, nullptr, aw2t, ab2, bufM, w, lane);
  __syncthreads();
  {
    int r = t>>3, seg = t&7;
    float p = 0.f;
    const unsigned short* row = bufM + r*128 + seg*16;
    const float* w3 = aw3 + seg*16;
    #pragma unroll
    for (int k=0;k<16;++k) p += h2f(row[k]) * w3[k];
    lp[r*8+seg] = p;
  }
  __syncthreads();
  if (t < 4){
    float lg[8]; float mx = -1e30f;
    for (int l=0;l<8;++l){
      float s = ab3[0];
      #pragma unroll
      for (int sg=0;sg<8;++sg) s += lp[(t*8+l)*8+sg];
      lg[l] = s; mx = fmaxf(mx, s);
    }
    float sum = 0.f;
    for (int l=0;l<8;++l){ lg[l] = __builtin_amdgcn_exp2f((lg[l]-mx)*1.44269504089f); sum += lg[l]; }
    float inv = __builtin_amdgcn_rcpf(sum);
    for (int l=0;l<8;++l) att_s[t*8+l] = lg[l]*inv;
  }
  __syncthreads();
  stage<4>(bufE, nullptr, vw1t, vb1, bufA, w, lane);
  __syncthreads();
  {
    #pragma unroll
    for (int obl=0; obl<2; ++obl){
      int col = ((w*2+obl)<<4) + (lane&15);
      f32x4 a0 = {0.f,0.f,0.f,0.f}, a1v = {0.f,0.f,0.f,0.f};
      #pragma unroll
      for (int s=0;s<4;++s){
        f16x8 bfr = *(const f16x8*)(vw2t + (size_t)col*128 + s*32 + ((lane>>4)<<3));
        a0  = mfma16(ldsA(bufA,0,s,lane), bfr, a0);
        a1v = mfma16(ldsA(bufA,1,s,lane), bfr, a1v);
      }
      float bb = vb2[col];
      #pragma unroll
      for (int reg=0;reg<4;++reg){
        int r0 = ((lane>>4)<<2) + reg;
        float v0 = tanh_fast(a0[reg]+bb);
        float v1 = tanh_fast(a1v[reg]+bb);
        atomicAdd(&fin[((r0)>>3)*128 + col],    att_s[r0]    * v0);
        atomicAdd(&fin[((16+r0)>>3)*128 + col], att_s[16+r0] * v1);
      }
    }
  }
  __syncthreads();
  for (int idx=t; idx<512; idx+=256){
    int b_loc = idx>>7, o = idx&127;
    outp[(size_t)(R0/8 + b_loc)*128 + o] = fin[idx];
  }
}

// ---------- launch ----------
extern "C" void kernel_launch(void* const* d_in, const int* in_sizes, int n_in,
                              void* d_out, int out_size, void* d_ws, size_t ws_size,
                              hipStream_t stream){
  const float* obs = (const float*)d_in[0];
  const float* hw1 = (const float*)d_in[3];
  const float* hb1 = (const float*)d_in[4];
  const float* hw2 = (const float*)d_in[5];
  const float* hb2 = (const float*)d_in[6];
  const float* vw1 = (const float*)d_in[7];
  const float* vb1 = (const float*)d_in[8];
  const float* vw2 = (const float*)d_in[9];
  const float* vb2 = (const float*)d_in[10];
  const float* aw1 = (const float*)d_in[11];
  const float* ab1 = (const float*)d_in[12];
  const float* aw2 = (const float*)d_in[13];
  const float* ab2 = (const float*)d_in[14];
  const float* aw3 = (const float*)d_in[15];
  const float* ab3 = (const float*)d_in[16];

  char* ws = (char*)d_ws;
  unsigned short* wt2    = (unsigned short*)(ws);             // 3,145,728 B
  unsigned short* mean16 = (unsigned short*)(ws);             //   262,144 B (alias; wt2 dead after k2)
  unsigned short* h16    = (unsigned short*)(ws + 3145728);   // 2,097,152 B
  float*          accg   = (float*)        (ws + 5242880);    // 4,194,304 B
  unsigned short* vw1t   = (unsigned short*)(ws + 9437184);   //    32,768 B
  unsigned short* vw2t   = (unsigned short*)(ws + 9469952);   //    32,768 B
  unsigned short* aw1t   = (unsigned short*)(ws + 9502720);   //    65,536 B
  unsigned short* aw2t   = (unsigned short*)(ws + 9568256);   //    32,768 B  (end 9,601,024)
  float* outp = (float*)d_out;

  hipMemsetAsync(accg, 0, 8192*128*sizeof(float), stream);
  prep_kernel<<<2128, 256, 0, stream>>>(obs, hw1, hb1, hw2, vw1, vw2, aw1, aw2,
                                        wt2, vw1t, vw2t, aw1t, aw2t, h16);
  k2_hyper<<<256, 512, 0, stream>>>(obs, h16, wt2, hb2, accg);
  k3_mean<<<256, 256, 0, stream>>>(accg, mean16);
  k4_mlp<<<256, 256, 0, stream>>>(accg, mean16, vw1t, vw2t, aw1t, aw2t,
                                  vb1, vb2, ab1, ab2, aw3, ab3, outp);
}

// Round 6
// 105.624 us; speedup vs baseline: 1.9380x; 1.1407x over previous
//
#include <hip/hip_runtime.h>

// ---------- types / helpers ----------
typedef _Float16 f16x8 __attribute__((ext_vector_type(8)));
typedef float f32x4 __attribute__((ext_vector_type(4)));

__device__ __forceinline__ float tanh_fast(float x){
  // tanh(x) = 1 - 2/(1+exp2(2*log2e*x)); exact at saturation
  float e = __builtin_amdgcn_exp2f(x * 2.88539008177793f);
  return 1.f - 2.f * __builtin_amdgcn_rcpf(1.f + e);
}
__device__ __forceinline__ unsigned short f2h(float f){
  return __builtin_bit_cast(unsigned short, (_Float16)f);
}
__device__ __forceinline__ float h2f(unsigned short u){
  return (float)__builtin_bit_cast(_Float16, u);
}
__device__ __forceinline__ f32x4 mfma16(f16x8 a, f16x8 b, f32x4 c){
  return __builtin_amdgcn_mfma_f32_16x16x32_f16(a, b, c, 0, 0, 0);
}

// A-fragment from an LDS [32][128] f16 tile.
__device__ __forceinline__ f16x8 ldsA(const unsigned short* buf, int rb, int s, int lane){
  return *(const f16x8*)(buf + (rb*16 + (lane&15))*128 + s*32 + ((lane>>4)<<3));
}

// ---------- PREP: all 5 weight transposes + k1 hidden, one launch ----------
__global__ __launch_bounds__(256) void prep_kernel(
    const float* __restrict__ obs, const float* __restrict__ hw1,
    const float* __restrict__ hb1, const float* __restrict__ hw2,
    const float* __restrict__ vw1, const float* __restrict__ vw2,
    const float* __restrict__ aw1, const float* __restrict__ aw2,
    unsigned short* __restrict__ wt2, unsigned short* __restrict__ vw1t,
    unsigned short* __restrict__ vw2t, unsigned short* __restrict__ aw1t,
    unsigned short* __restrict__ aw2t, unsigned short* __restrict__ h16){
  int b = blockIdx.x, t = threadIdx.x;
  if (b < 1616){
    __shared__ float tile[32][33];
    const float* in; unsigned short* out; int R, C, bx, by;
    if (b < 1536)      { in=hw2; out=wt2;  R=128; C=12288; bx=b%384;      by=b/384; }
    else if (b < 1552) { int q=b-1536; in=vw1; out=vw1t; R=128; C=128; bx=q&3; by=q>>2; }
    else if (b < 1568) { int q=b-1552; in=vw2; out=vw2t; R=128; C=128; bx=q&3; by=q>>2; }
    else if (b < 1600) { int q=b-1568; in=aw1; out=aw1t; R=256; C=128; bx=q&3; by=q>>2; }
    else               { int q=b-1600; in=aw2; out=aw2t; R=128; C=128; bx=q&3; by=q>>2; }
    int c0=bx*32, r0=by*32, tx=t&31, ty=t>>5;
    #pragma unroll
    for (int j=ty; j<32; j+=8) tile[j][tx] = in[(size_t)(r0+j)*C + c0 + tx];
    __syncthreads();
    #pragma unroll
    for (int j=ty; j<32; j+=8) out[(size_t)(c0+j)*R + r0 + tx] = f2h(tile[tx][j]);
  } else {
    __shared__ float w_s[96*128];
    __shared__ float x_s[16*96];
    __shared__ float b_s[128];
    int n0 = (b-1616)*16;
    for (int idx=t; idx<96*128; idx+=256) w_s[idx] = hw1[idx];
    if (t < 128) b_s[t] = hb1[t];
    for (int idx=t; idx<16*96; idx+=256){
      int r = idx/96, i = idx - r*96;
      int n = n0 + r; int bb = n>>3, l = n&7;
      x_s[idx] = (i<64) ? obs[bb*360 + i] : obs[bb*360 + 104 + (l<<5) + (i-64)];
    }
    __syncthreads();
    for (int e=t; e<16*128; e+=256){
      int r = e>>7, o = e&127;
      float acc = b_s[o];
      const float* xr = &x_s[r*96];
      #pragma unroll 4
      for (int i=0;i<96;++i) acc = fmaf(xr[i], w_s[i*128+o], acc);
      h16[(size_t)(n0+r)*128 + o] = f2h(tanh_fast(acc));
    }
  }
}

// ---------- K2: fused hypernet GEMM + tanh + x-contraction ----------
// grid 256: blockIdx = rowTile*2 + iHalf. 64 rows/block, i in [ih*48, +48).
// 8 waves own 16 output cols each for all 4 row-blocks.
// Register budget (fits 128 arch VGPRs): af[4][4]=64, B dbuf=32, facc=16, addr ~14.
__global__ __launch_bounds__(512, 2) void k2_hyper(const float* __restrict__ obs,
    const unsigned short* __restrict__ h16, const unsigned short* __restrict__ wt2,
    const float* __restrict__ hb2, float* __restrict__ accg){
  __shared__ float x_s[48*64];   // [i_local][row]
  int t = threadIdx.x, lane = t & 63, w = t >> 6;
  int rt = blockIdx.x >> 1, ih = blockIdx.x & 1;
  int R0 = rt*64, ibase = ih*48;
  int wcol = w*16 + (lane&15);
  int kof  = (lane>>4) << 3;
  int rloc = (lane>>4) << 2;

  for (int idx=t; idx<48*64; idx+=512){
    int il = idx>>6, r = idx&63;
    int i = ibase + il;
    int n = R0 + r; int bb = n>>3, l = n&7;
    x_s[idx] = (i<64) ? obs[bb*360 + i] : obs[bb*360 + 104 + (l<<5) + (i-64)];
  }

  // A fragments for 4 row-blocks of 16 rows (i-invariant, held in registers)
  f16x8 af[4][4];
  #pragma unroll
  for (int rb=0; rb<4; ++rb)
    #pragma unroll
    for (int s=0; s<4; ++s)
      af[rb][s] = *(const f16x8*)(h16 + (size_t)(R0 + rb*16 + (lane&15))*128 + s*32 + kof);

  __syncthreads();

  float facc[4][4];
  #pragma unroll
  for (int rb=0;rb<4;++rb)
    #pragma unroll
    for (int reg=0;reg<4;++reg) facc[rb][reg] = 0.f;

  const unsigned short* wp = wt2 + (size_t)(ibase*128 + wcol)*128 + kof;
  const float* bp = hb2 + ibase*128 + wcol;

  f16x8 A0,A1,A2,A3, B0,B1,B2,B3;
  float biasA, biasB;

#define K2L(X0,X1,X2,X3,BI) do{                 \
    X0 = *(const f16x8*)(wp);                   \
    X1 = *(const f16x8*)(wp+32);                \
    X2 = *(const f16x8*)(wp+64);                \
    X3 = *(const f16x8*)(wp+96);                \
    BI = *bp;                                   \
    wp += 16384; bp += 128;                     \
  }while(0)

#define K2C(X0,X1,X2,X3,BI,IL) do{                                       \
    _Pragma("unroll")                                                    \
    for (int rb=0; rb<4; rb+=2){                                         \
      f32x4 a0 = {BI,BI,BI,BI}, a1 = {BI,BI,BI,BI};                      \
      a0 = mfma16(af[rb][0], X0, a0); a1 = mfma16(af[rb+1][0], X0, a1);  \
      a0 = mfma16(af[rb][1], X1, a0); a1 = mfma16(af[rb+1][1], X1, a1);  \
      a0 = mfma16(af[rb][2], X2, a0); a1 = mfma16(af[rb+1][2], X2, a1);  \
      a0 = mfma16(af[rb][3], X3, a0); a1 = mfma16(af[rb+1][3], X3, a1);  \
      f32x4 x0 = *(const f32x4*)(x_s + (IL)*64 + rb*16 + rloc);          \
      f32x4 x1 = *(const f32x4*)(x_s + (IL)*64 + (rb+1)*16 + rloc);      \
      _Pragma("unroll")                                                  \
      for (int reg=0; reg<4; ++reg){                                     \
        facc[rb][reg]   = fmaf(x0[reg], tanh_fast(a0[reg]), facc[rb][reg]);   \
        facc[rb+1][reg] = fmaf(x1[reg], tanh_fast(a1[reg]), facc[rb+1][reg]); \
      }                                                                  \
    }                                                                    \
  }while(0)

  K2L(A0,A1,A2,A3,biasA);
  K2L(B0,B1,B2,B3,biasB);
  for (int il=0; il<46; il+=2){
    K2C(A0,A1,A2,A3,biasA,il);
    K2L(A0,A1,A2,A3,biasA);
    K2C(B0,B1,B2,B3,biasB,il+1);
    K2L(B0,B1,B2,B3,biasB);
  }
  K2C(A0,A1,A2,A3,biasA,46);
  K2C(B0,B1,B2,B3,biasB,47);
#undef K2L
#undef K2C

  #pragma unroll
  for (int rb=0; rb<4; ++rb)
    #pragma unroll
    for (int reg=0; reg<4; ++reg)
      atomicAdd(&accg[(size_t)(R0 + rb*16 + rloc + reg)*128 + wcol], facc[rb][reg]);
}

// ---------- K3: per-batch landmark mean of tanh(accg) -> mean16 ----------
__global__ __launch_bounds__(256) void k3_mean(const float* __restrict__ accg,
    unsigned short* __restrict__ mean16){
  int t = threadIdx.x, B0 = blockIdx.x*4;
  for (int task=t; task<512; task+=256){
    int bl = task>>7, o = task&127;
    float m = 0.f;
    #pragma unroll
    for (int l=0;l<8;++l)
      m += tanh_fast(accg[(size_t)((B0 + bl)*8 + l)*128 + o]);
    mean16[(size_t)(B0 + bl)*128 + o] = f2h(m * 0.125f);
  }
}

// ---------- K4: emb from accg + fused MLP chain + softmax + final ----------
template<int KS>
__device__ __forceinline__ void stage(const unsigned short* inA, const unsigned short* inB,
    const unsigned short* wt, const float* bias, unsigned short* outb, int w, int lane){
  #pragma unroll
  for (int obl=0; obl<2; ++obl){
    int col = ((w*2+obl)<<4) + (lane&15);
    f32x4 a0 = {0.f,0.f,0.f,0.f}, a1v = {0.f,0.f,0.f,0.f};
    #pragma unroll
    for (int s=0;s<KS;++s){
      f16x8 bfr = *(const f16x8*)(wt + (size_t)col*(KS*32) + s*32 + ((lane>>4)<<3));
      f16x8 aa0, aa1;
      if (KS==8 && s>=4){ aa0 = ldsA(inB,0,s-4,lane); aa1 = ldsA(inB,1,s-4,lane); }
      else              { aa0 = ldsA(inA,0,s,lane);   aa1 = ldsA(inA,1,s,lane);   }
      a0  = mfma16(aa0, bfr, a0);
      a1v = mfma16(aa1, bfr, a1v);
    }
    float bb = bias[col];
    #pragma unroll
    for (int reg=0;reg<4;++reg){
      int r0 = ((lane>>4)<<2) + reg;
      outb[r0*128 + col]      = f2h(tanh_fast(a0[reg] + bb));
      outb[(16+r0)*128 + col] = f2h(tanh_fast(a1v[reg] + bb));
    }
  }
}

__global__ __launch_bounds__(256) void k4_mlp(
    const float* __restrict__ accg, const unsigned short* __restrict__ mean16,
    const unsigned short* __restrict__ vw1t, const unsigned short* __restrict__ vw2t,
    const unsigned short* __restrict__ aw1t, const unsigned short* __restrict__ aw2t,
    const float* __restrict__ vb1, const float* __restrict__ vb2,
    const float* __restrict__ ab1, const float* __restrict__ ab2,
    const float* __restrict__ aw3, const float* __restrict__ ab3,
    float* __restrict__ outp){
  __shared__ unsigned short bufE[32*128];
  __shared__ unsigned short bufM[32*128];
  __shared__ unsigned short bufA[32*128];
  __shared__ float fin[4*128];
  __shared__ float lp[32*8];
  __shared__ float att_s[32];
  int t = threadIdx.x, lane = t&63, w = t>>6;
  int R0 = blockIdx.x*32;

  // emb = tanh(accg) for our 32 rows
  for (int idx=t; idx<4096; idx+=256)
    bufE[idx] = f2h(tanh_fast(accg[(size_t)R0*128 + idx]));
  // mean_rep faithful ordering: row n pairs with mean[(n % 1024)]
  for (int idx=t; idx<512; idx+=256){
    int r = idx>>4, c8 = (idx&15)<<3;
    int n = R0 + r;
    *(uint4*)(bufM + r*128 + c8) = *(const uint4*)(mean16 + (size_t)(n & 1023)*128 + c8);
  }
  for (int idx=t; idx<512; idx+=256) fin[idx] = 0.f;
  __syncthreads();

  stage<8>(bufE, bufM, aw1t, ab1, bufA, w, lane);
  __syncthreads();
  stage<4>(bufA, nullptr, aw2t, ab2, bufM, w, lane);
  __syncthreads();
  {
    int r = t>>3, seg = t&7;
    float p = 0.f;
    const unsigned short* row = bufM + r*128 + seg*16;
    const float* w3 = aw3 + seg*16;
    #pragma unroll
    for (int k=0;k<16;++k) p += h2f(row[k]) * w3[k];
    lp[r*8+seg] = p;
  }
  __syncthreads();
  if (t < 4){
    float lg[8]; float mx = -1e30f;
    for (int l=0;l<8;++l){
      float s = ab3[0];
      #pragma unroll
      for (int sg=0;sg<8;++sg) s += lp[(t*8+l)*8+sg];
      lg[l] = s; mx = fmaxf(mx, s);
    }
    float sum = 0.f;
    for (int l=0;l<8;++l){ lg[l] = __builtin_amdgcn_exp2f((lg[l]-mx)*1.44269504089f); sum += lg[l]; }
    float inv = __builtin_amdgcn_rcpf(sum);
    for (int l=0;l<8;++l) att_s[t*8+l] = lg[l]*inv;
  }
  __syncthreads();
  stage<4>(bufE, nullptr, vw1t, vb1, bufA, w, lane);
  __syncthreads();
  {
    #pragma unroll
    for (int obl=0; obl<2; ++obl){
      int col = ((w*2+obl)<<4) + (lane&15);
      f32x4 a0 = {0.f,0.f,0.f,0.f}, a1v = {0.f,0.f,0.f,0.f};
      #pragma unroll
      for (int s=0;s<4;++s){
        f16x8 bfr = *(const f16x8*)(vw2t + (size_t)col*128 + s*32 + ((lane>>4)<<3));
        a0  = mfma16(ldsA(bufA,0,s,lane), bfr, a0);
        a1v = mfma16(ldsA(bufA,1,s,lane), bfr, a1v);
      }
      float bb = vb2[col];
      #pragma unroll
      for (int reg=0;reg<4;++reg){
        int r0 = ((lane>>4)<<2) + reg;
        float v0 = tanh_fast(a0[reg]+bb);
        float v1 = tanh_fast(a1v[reg]+bb);
        atomicAdd(&fin[((r0)>>3)*128 + col],    att_s[r0]    * v0);
        atomicAdd(&fin[((16+r0)>>3)*128 + col], att_s[16+r0] * v1);
      }
    }
  }
  __syncthreads();
  for (int idx=t; idx<512; idx+=256){
    int b_loc = idx>>7, o = idx&127;
    outp[(size_t)(R0/8 + b_loc)*128 + o] = fin[idx];
  }
}

// ---------- launch ----------
extern "C" void kernel_launch(void* const* d_in, const int* in_sizes, int n_in,
                              void* d_out, int out_size, void* d_ws, size_t ws_size,
                              hipStream_t stream){
  const float* obs = (const float*)d_in[0];
  const float* hw1 = (const float*)d_in[3];
  const float* hb1 = (const float*)d_in[4];
  const float* hw2 = (const float*)d_in[5];
  const float* hb2 = (const float*)d_in[6];
  const float* vw1 = (const float*)d_in[7];
  const float* vb1 = (const float*)d_in[8];
  const float* vw2 = (const float*)d_in[9];
  const float* vb2 = (const float*)d_in[10];
  const float* aw1 = (const float*)d_in[11];
  const float* ab1 = (const float*)d_in[12];
  const float* aw2 = (const float*)d_in[13];
  const float* ab2 = (const float*)d_in[14];
  const float* aw3 = (const float*)d_in[15];
  const float* ab3 = (const float*)d_in[16];

  char* ws = (char*)d_ws;
  unsigned short* wt2    = (unsigned short*)(ws);             // 3,145,728 B
  unsigned short* mean16 = (unsigned short*)(ws);             //   262,144 B (alias; wt2 dead after k2)
  unsigned short* h16    = (unsigned short*)(ws + 3145728);   // 2,097,152 B
  float*          accg   = (float*)        (ws + 5242880);    // 4,194,304 B
  unsigned short* vw1t   = (unsigned short*)(ws + 9437184);   //    32,768 B
  unsigned short* vw2t   = (unsigned short*)(ws + 9469952);   //    32,768 B
  unsigned short* aw1t   = (unsigned short*)(ws + 9502720);   //    65,536 B
  unsigned short* aw2t   = (unsigned short*)(ws + 9568256);   //    32,768 B  (end 9,601,024)
  float* outp = (float*)d_out;

  hipMemsetAsync(accg, 0, 8192*128*sizeof(float), stream);
  prep_kernel<<<2128, 256, 0, stream>>>(obs, hw1, hb1, hw2, vw1, vw2, aw1, aw2,
                                        wt2, vw1t, vw2t, aw1t, aw2t, h16);
  k2_hyper<<<256, 512, 0, stream>>>(obs, h16, wt2, hb2, accg);
  k3_mean<<<256, 256, 0, stream>>>(accg, mean16);
  k4_mlp<<<256, 256, 0, stream>>>(accg, mean16, vw1t, vw2t, aw1t, aw2t,
                                  vb1, vb2, ab1, ab2, aw3, ab3, outp);
}